// Round 9
// baseline (267.931 us; speedup 1.0000x reference)
//
#include <hip/hip_runtime.h>

typedef __attribute__((ext_vector_type(8))) short bf16x8;
typedef __attribute__((ext_vector_type(4))) float f32x4;

__device__ __forceinline__ float bf2f(unsigned short u) {
    unsigned int x = ((unsigned int)u) << 16;
    float f;
    __builtin_memcpy(&f, &x, 4);
    return f;
}
__device__ __forceinline__ unsigned short f2bf(float f) {
    unsigned int x;
    __builtin_memcpy(&x, &f, 4);
    x += 0x7FFFu + ((x >> 16) & 1u);
    return (unsigned short)(x >> 16);
}

// -------------------------------------------------------------------------
__global__ __launch_bounds__(256) void cast_f32_bf16(
    const float* __restrict__ in, unsigned short* __restrict__ out, int n) {
    int i = (blockIdx.x * 256 + threadIdx.x) * 4;
    if (i >= n) return;
    float4 v = *(const float4*)(in + i);
    out[i + 0] = f2bf(v.x);
    out[i + 1] = f2bf(v.y);
    out[i + 2] = f2bf(v.z);
    out[i + 3] = f2bf(v.w);
}

// -------------------------------------------------------------------------
__global__ __launch_bounds__(256) void zero_f32(float* __restrict__ p, int n4) {
    int i = blockIdx.x * 256 + threadIdx.x;
    if (i < n4) *(float4*)(p + i * 4) = (float4){0.f, 0.f, 0.f, 0.f};
}

// -------------------------------------------------------------------------
// W_eff[n][k] = bf16( W[n][k] + (1/16) * sum_r BB[n][r] * A[r][k] ), f32 in.
__global__ __launch_bounds__(256) void fold_lora(
    const float* __restrict__ W, const float* __restrict__ Ain,
    const float* __restrict__ Bin, unsigned short* __restrict__ Weff, int NK) {
    int idx = blockIdx.x * 256 + threadIdx.x;
    if (idx >= NK) return;
    int n = idx >> 10;
    int k = idx & 1023;
    float s = 0.f;
#pragma unroll
    for (int r = 0; r < 16; ++r)
        s += Bin[n * 16 + r] * Ain[r * 1024 + k];
    Weff[idx] = f2bf(W[idx] + 0.0625f * s);
}

// -------------------------------------------------------------------------
// C[M][N] = A@B^T + bias. 128x128 tile (gemm1 / qkv). bf16 out.
__global__ __launch_bounds__(256) void gemm_bt_bias(
    const unsigned short* __restrict__ A, const unsigned short* __restrict__ B,
    const float* __restrict__ bias, unsigned short* __restrict__ Cb,
    int M, int N, int K) {
    __shared__ unsigned short sA[128 * 32];
    __shared__ unsigned short sB[128 * 32];
    const int tid = threadIdx.x;
    const int wave = tid >> 6, lane = tid & 63;
    const int quad = lane >> 4, l16 = lane & 15;
    const int m0 = blockIdx.y * 128, n0 = blockIdx.x * 128;
    const int wm = (wave & 1) * 64, wn = (wave >> 1) * 64;

    const int srow = wave * 32 + (lane >> 2);
    const int scol = (lane & 3) * 8;
    const unsigned short* Ag = A + (size_t)(m0 + srow) * K + scol;
    const unsigned short* Bg = B + (size_t)(n0 + srow) * K + scol;
    unsigned short* sAw = sA + wave * 1024;
    unsigned short* sBw = sB + wave * 1024;
    const size_t kjump = (size_t)16 * K;

    f32x4 acc[4][4];
#pragma unroll
    for (int i = 0; i < 4; ++i)
#pragma unroll
        for (int j = 0; j < 4; ++j) acc[i][j] = (f32x4){0.f, 0.f, 0.f, 0.f};

    for (int k0 = 0; k0 < K; k0 += 32) {
        bf16x8 va0 = *(const bf16x8*)(Ag + k0);
        bf16x8 va1 = *(const bf16x8*)(Ag + k0 + kjump);
        bf16x8 vb0 = *(const bf16x8*)(Bg + k0);
        bf16x8 vb1 = *(const bf16x8*)(Bg + k0 + kjump);
        __syncthreads();
        *(bf16x8*)(sAw + (size_t)lane * 8) = va0;
        *(bf16x8*)(sAw + 512 + (size_t)lane * 8) = va1;
        *(bf16x8*)(sBw + (size_t)lane * 8) = vb0;
        *(bf16x8*)(sBw + 512 + (size_t)lane * 8) = vb1;
        __syncthreads();
        bf16x8 af[4], bfr[4];
#pragma unroll
        for (int mi = 0; mi < 4; ++mi)
            af[mi] = *(const bf16x8*)&sA[(wm + mi * 16 + l16) * 32 + quad * 8];
#pragma unroll
        for (int ni = 0; ni < 4; ++ni)
            bfr[ni] = *(const bf16x8*)&sB[(wn + ni * 16 + l16) * 32 + quad * 8];
#pragma unroll
        for (int mi = 0; mi < 4; ++mi)
#pragma unroll
            for (int ni = 0; ni < 4; ++ni)
                acc[mi][ni] = __builtin_amdgcn_mfma_f32_16x16x32_bf16(
                    af[mi], bfr[ni], acc[mi][ni], 0, 0, 0);
    }
    float bv[4];
#pragma unroll
    for (int ni = 0; ni < 4; ++ni) bv[ni] = bias[n0 + wn + ni * 16 + l16];
#pragma unroll
    for (int mi = 0; mi < 4; ++mi)
#pragma unroll
        for (int ni = 0; ni < 4; ++ni)
#pragma unroll
            for (int r = 0; r < 4; ++r) {
                int row = m0 + wm + mi * 16 + quad * 4 + r;
                int col = n0 + wn + ni * 16 + l16;
                Cb[(size_t)row * N + col] = f2bf(acc[mi][ni][r] + bv[ni]);
            }
}

// -------------------------------------------------------------------------
// 64x64-tile GEMM (proj): grid (16,64) = 1024 blocks -> 4 blocks/CU. f32 out.
// Exonerated by r6/r7 vs r8 bit-identical absmax (same K-order as 128-tile).
__global__ __launch_bounds__(256) void gemm_bt_bias64(
    const unsigned short* __restrict__ A, const unsigned short* __restrict__ B,
    const float* __restrict__ bias, float* __restrict__ Cf,
    int M, int N, int K) {
    __shared__ unsigned short sA[64 * 32];
    __shared__ unsigned short sB[64 * 32];
    const int tid = threadIdx.x;
    const int wave = tid >> 6, lane = tid & 63;
    const int quad = lane >> 4, l16 = lane & 15;
    const int m0 = blockIdx.y * 64, n0 = blockIdx.x * 64;
    const int wm = (wave & 1) * 32, wn = (wave >> 1) * 32;

    const int srow = tid >> 2;
    const int scol = (tid & 3) * 8;
    const unsigned short* Ag = A + (size_t)(m0 + srow) * K + scol;
    const unsigned short* Bg = B + (size_t)(n0 + srow) * K + scol;

    f32x4 acc[2][2];
#pragma unroll
    for (int i = 0; i < 2; ++i)
#pragma unroll
        for (int j = 0; j < 2; ++j) acc[i][j] = (f32x4){0.f, 0.f, 0.f, 0.f};

    for (int k0 = 0; k0 < K; k0 += 32) {
        bf16x8 va = *(const bf16x8*)(Ag + k0);
        bf16x8 vb = *(const bf16x8*)(Bg + k0);
        __syncthreads();
        *(bf16x8*)&sA[srow * 32 + scol] = va;
        *(bf16x8*)&sB[srow * 32 + scol] = vb;
        __syncthreads();
        bf16x8 af[2], bfr[2];
#pragma unroll
        for (int mi = 0; mi < 2; ++mi)
            af[mi] = *(const bf16x8*)&sA[(wm + mi * 16 + l16) * 32 + quad * 8];
#pragma unroll
        for (int ni = 0; ni < 2; ++ni)
            bfr[ni] = *(const bf16x8*)&sB[(wn + ni * 16 + l16) * 32 + quad * 8];
#pragma unroll
        for (int mi = 0; mi < 2; ++mi)
#pragma unroll
            for (int ni = 0; ni < 2; ++ni)
                acc[mi][ni] = __builtin_amdgcn_mfma_f32_16x16x32_bf16(
                    af[mi], bfr[ni], acc[mi][ni], 0, 0, 0);
    }
    float bv[2];
#pragma unroll
    for (int ni = 0; ni < 2; ++ni) bv[ni] = bias[n0 + wn + ni * 16 + l16];
#pragma unroll
    for (int mi = 0; mi < 2; ++mi)
#pragma unroll
        for (int ni = 0; ni < 2; ++ni)
#pragma unroll
            for (int r = 0; r < 4; ++r) {
                int row = m0 + wm + mi * 16 + quad * 4 + r;
                int col = n0 + wn + ni * 16 + l16;
                Cf[(size_t)row * N + col] = acc[mi][ni][r] + bv[ni];
            }
}

// -------------------------------------------------------------------------
// Vt[(b*16+h)][d][t] = qkv[b*2048+t][2048 + h*64 + d]   (bf16, verified)
__global__ __launch_bounds__(256) void transpose_v(
    const unsigned short* __restrict__ qkv, unsigned short* __restrict__ Vt) {
    const int b = blockIdx.z, h = blockIdx.y, t0 = blockIdx.x * 64;
    __shared__ unsigned short tile[64][68];
    const int tid = threadIdx.x;
    const int r = tid >> 3, c8 = (tid & 7) * 8;
    const unsigned short* src = qkv + (size_t)(b * 2048) * 3072 + 2048 + h * 64;
#pragma unroll
    for (int p = 0; p < 2; ++p) {
        int t = p * 32 + r;
        const unsigned short* s = src + (size_t)(t0 + t) * 3072 + c8;
#pragma unroll
        for (int j = 0; j < 8; ++j) tile[t][c8 + j] = s[j];
    }
    __syncthreads();
    unsigned short* dst = Vt + (size_t)((b * 16 + h) * 64) * 2048;
#pragma unroll
    for (int p = 0; p < 2; ++p) {
        int d = p * 32 + r;
        unsigned short* o = dst + (size_t)d * 2048 + t0 + c8;
#pragma unroll
        for (int j = 0; j < 8; ++j) o[j] = tile[c8 + j][d];
    }
}

// -------------------------------------------------------------------------
// Split-KV flash attention. qblk = bx>>2, chunk c = bx&3 (8 kv-tiles each);
// empty chunks exit early. Partials exactly additive (no online max).
// Denominator accumulator lag is PER (row, head): lag[row*16 + h].
__global__ __launch_bounds__(256) void attn_chunk(
    const unsigned short* __restrict__ qkv,  // [4096][3072] bf16
    const unsigned short* __restrict__ Vt,   // [32][64][2048] bf16
    float* __restrict__ oacc,                // [4096][1024] f32 (zeroed)
    float* __restrict__ lag) {               // [4096][16] f32 (zeroed)
    const int b = blockIdx.z, h = blockIdx.y;
    const int qblk = blockIdx.x >> 2;
    const int c = blockIdx.x & 3;
    const int t0 = c * 8;
    if (t0 > qblk) return;  // block-uniform early exit
    const int t1 = min(t0 + 8, qblk + 1);

    const int w = threadIdx.x >> 6, lane = threadIdx.x & 63;
    const int quad = lane >> 4, l16 = lane & 15;
    const int q0 = qblk * 64 + w * 16;

    __shared__ unsigned short sK[64 * 72];
    __shared__ unsigned short sV[64 * 72];
    __shared__ unsigned short sP[4][16 * 72];

    const unsigned short* Qb = qkv + (size_t)(b * 2048) * 3072 + h * 64;
    const unsigned short* Kg = Qb + 1024;
    const unsigned short* Vg = Vt + (size_t)((b * 16 + h) * 64) * 2048;

    const int rlo = threadIdx.x >> 3;
    const int c8 = (threadIdx.x & 7) * 8;

    bf16x8 qf0 = *(const bf16x8*)(Qb + (size_t)(q0 + l16) * 3072 + quad * 8);
    bf16x8 qf1 = *(const bf16x8*)(Qb + (size_t)(q0 + l16) * 3072 + 32 + quad * 8);

    f32x4 o[4];
    float lacc[4];
#pragma unroll
    for (int nt = 0; nt < 4; ++nt) o[nt] = (f32x4){0.f, 0.f, 0.f, 0.f};
#pragma unroll
    for (int r = 0; r < 4; ++r) lacc[r] = 0.f;

    const float csc = 0.125f * 1.44269504088896340736f;

    bf16x8 kr0 = *(const bf16x8*)(Kg + (size_t)(t0 * 64 + rlo) * 3072 + c8);
    bf16x8 kr1 = *(const bf16x8*)(Kg + (size_t)(t0 * 64 + rlo + 32) * 3072 + c8);
    bf16x8 vr0 = *(const bf16x8*)(Vg + (size_t)rlo * 2048 + t0 * 64 + c8);
    bf16x8 vr1 = *(const bf16x8*)(Vg + (size_t)(rlo + 32) * 2048 + t0 * 64 + c8);

    for (int it = t0; it < t1; ++it) {
        const int kv0 = it * 64;
        __syncthreads();
        *(bf16x8*)&sK[rlo * 72 + c8] = kr0;
        *(bf16x8*)&sK[(rlo + 32) * 72 + c8] = kr1;
        *(bf16x8*)&sV[rlo * 72 + c8] = vr0;
        *(bf16x8*)&sV[(rlo + 32) * 72 + c8] = vr1;
        if (it + 1 < t1) {
            const int nx = kv0 + 64;
            kr0 = *(const bf16x8*)(Kg + (size_t)(nx + rlo) * 3072 + c8);
            kr1 = *(const bf16x8*)(Kg + (size_t)(nx + rlo + 32) * 3072 + c8);
            vr0 = *(const bf16x8*)(Vg + (size_t)rlo * 2048 + nx + c8);
            vr1 = *(const bf16x8*)(Vg + (size_t)(rlo + 32) * 2048 + nx + c8);
        }
        __syncthreads();

        f32x4 S[4];
#pragma unroll
        for (int f = 0; f < 4; ++f) {
            bf16x8 klo = *(const bf16x8*)&sK[(f * 16 + l16) * 72 + quad * 8];
            bf16x8 khi = *(const bf16x8*)&sK[(f * 16 + l16) * 72 + 32 + quad * 8];
            S[f] = (f32x4){0.f, 0.f, 0.f, 0.f};
            S[f] = __builtin_amdgcn_mfma_f32_16x16x32_bf16(qf0, klo, S[f], 0, 0, 0);
            S[f] = __builtin_amdgcn_mfma_f32_16x16x32_bf16(qf1, khi, S[f], 0, 0, 0);
        }
        if (it == qblk) {
#pragma unroll
            for (int f = 0; f < 4; ++f)
#pragma unroll
                for (int r = 0; r < 4; ++r) {
                    int col = kv0 + f * 16 + l16;
                    int qr = q0 + quad * 4 + r;
                    float p = (col <= qr) ? exp2f(S[f][r] * csc) : 0.f;
                    lacc[r] += p;
                    sP[w][(quad * 4 + r) * 72 + f * 16 + l16] = f2bf(p);
                }
        } else {
#pragma unroll
            for (int f = 0; f < 4; ++f)
#pragma unroll
                for (int r = 0; r < 4; ++r) {
                    float p = exp2f(S[f][r] * csc);
                    lacc[r] += p;
                    sP[w][(quad * 4 + r) * 72 + f * 16 + l16] = f2bf(p);
                }
        }
        asm volatile("" ::: "memory");
        bf16x8 pf0 = *(const bf16x8*)&sP[w][l16 * 72 + quad * 8];
        bf16x8 pf1 = *(const bf16x8*)&sP[w][l16 * 72 + 32 + quad * 8];
#pragma unroll
        for (int nt = 0; nt < 4; ++nt) {
            bf16x8 v0 = *(const bf16x8*)&sV[(nt * 16 + l16) * 72 + quad * 8];
            bf16x8 v1 = *(const bf16x8*)&sV[(nt * 16 + l16) * 72 + 32 + quad * 8];
            o[nt] = __builtin_amdgcn_mfma_f32_16x16x32_bf16(pf0, v0, o[nt], 0, 0, 0);
            o[nt] = __builtin_amdgcn_mfma_f32_16x16x32_bf16(pf1, v1, o[nt], 0, 0, 0);
        }
    }

    float lt[4];
#pragma unroll
    for (int r = 0; r < 4; ++r) lt[r] = lacc[r];
#pragma unroll
    for (int d = 1; d < 16; d <<= 1)
#pragma unroll
        for (int r = 0; r < 4; ++r) lt[r] += __shfl_xor(lt[r], d);
    if (l16 == 0) {
#pragma unroll
        for (int r = 0; r < 4; ++r)
            atomicAdd(&lag[(b * 2048 + q0 + quad * 4 + r) * 16 + h], lt[r]);
    }
    float* ob = oacc + (size_t)(b * 2048) * 1024 + h * 64;
#pragma unroll
    for (int nt = 0; nt < 4; ++nt)
#pragma unroll
        for (int r = 0; r < 4; ++r)
            atomicAdd(&ob[(size_t)(q0 + quad * 4 + r) * 1024 + nt * 16 + l16],
                      o[nt][r]);
}

// -------------------------------------------------------------------------
// y_bf16[row][ch] = oacc[row][ch] / lag[row*16 + ch/64]
__global__ __launch_bounds__(256) void attn_final(
    const float* __restrict__ oacc, const float* __restrict__ lag,
    unsigned short* __restrict__ y, int n) {
    int i = (blockIdx.x * 256 + threadIdx.x) * 4;
    if (i >= n) return;
    float4 v = *(const float4*)(oacc + i);
    int row = i >> 10, ch = i & 1023;
    float inv = 1.0f / lag[row * 16 + (ch >> 6)];
    y[i + 0] = f2bf(v.x * inv);
    y[i + 1] = f2bf(v.y * inv);
    y[i + 2] = f2bf(v.z * inv);
    y[i + 3] = f2bf(v.w * inv);
}

// -------------------------------------------------------------------------
extern "C" void kernel_launch(void* const* d_in, const int* in_sizes, int n_in,
                              void* d_out, int out_size, void* d_ws, size_t ws_size,
                              hipStream_t stream) {
    const float* x       = (const float*)d_in[0];
    const float* w_attn  = (const float*)d_in[1];
    const float* b_attn  = (const float*)d_in[2];
    const float* la_attn = (const float*)d_in[3];
    const float* lb_attn = (const float*)d_in[4];
    const float* w_proj  = (const float*)d_in[5];
    const float* b_proj  = (const float*)d_in[6];
    const float* la_proj = (const float*)d_in[7];
    const float* lb_proj = (const float*)d_in[8];
    float* out = (float*)d_out;

    // Workspace aliased by lifetime; total ~52.7 MB.
    char* w = (char*)d_ws;
    unsigned short* qkv       = (unsigned short*)(w);             // 24 MB [gemm1..attn_chunk]
    unsigned short* Vt        = (unsigned short*)(w + 25165824);  //  8 MB [transpose..attn_chunk]
    unsigned short* Weff_proj = (unsigned short*)(w + 33554432);  //  2 MB [fold..gemm2]
    char* pool = w + 35651584;                                    // 16.25 MB, two lifetimes:
    unsigned short* xb        = (unsigned short*)(pool);           // 8 MB [cast..gemm1]
    unsigned short* Weff_attn = (unsigned short*)(pool + 8388608); // 6 MB [fold..gemm1]
    float* oacc               = (float*)(pool);                    // 16 MB [zero..attn_final]
    float* lag                = (float*)(pool + 16777216);         // 256 KB (per row,head)
    unsigned short* y = qkv;  // alias; qkv dead after attn_chunk

    cast_f32_bf16<<<4096, 256, 0, stream>>>(x, xb, 4096 * 1024);
    fold_lora<<<(3072 * 1024) / 256, 256, 0, stream>>>(w_attn, la_attn, lb_attn,
                                                       Weff_attn, 3072 * 1024);
    fold_lora<<<(1024 * 1024) / 256, 256, 0, stream>>>(w_proj, la_proj, lb_proj,
                                                       Weff_proj, 1024 * 1024);
    gemm_bt_bias<<<dim3(24, 32), 256, 0, stream>>>(xb, Weff_attn, b_attn, qkv,
                                                   4096, 3072, 1024);
    // pool's first lifetime (xb, Weff_attn) ends; zero it for oacc+lag
    const int accn = 4096 * 1024 + 4096 * 16;  // oacc + lag, contiguous
    zero_f32<<<(accn / 4 + 255) / 256, 256, 0, stream>>>(oacc, accn / 4);
    transpose_v<<<dim3(32, 16, 2), 256, 0, stream>>>(qkv, Vt);
    attn_chunk<<<dim3(128, 16, 2), 256, 0, stream>>>(qkv, Vt, oacc, lag);
    attn_final<<<4096, 256, 0, stream>>>(oacc, lag, y, 4096 * 1024);
    gemm_bt_bias64<<<dim3(16, 64), 256, 0, stream>>>(y, Weff_proj, b_proj, out,
                                                     4096, 1024, 1024);
}

// Round 10
// 262.704 us; speedup vs baseline: 1.0199x; 1.0199x over previous
//
#include <hip/hip_runtime.h>

typedef __attribute__((ext_vector_type(8))) short bf16x8;
typedef __attribute__((ext_vector_type(4))) short bf16x4;
typedef __attribute__((ext_vector_type(4))) float f32x4;

__device__ __forceinline__ float bf2f(unsigned short u) {
    unsigned int x = ((unsigned int)u) << 16;
    float f;
    __builtin_memcpy(&f, &x, 4);
    return f;
}
__device__ __forceinline__ unsigned short f2bf(float f) {
    unsigned int x;
    __builtin_memcpy(&x, &f, 4);
    x += 0x7FFFu + ((x >> 16) & 1u);
    return (unsigned short)(x >> 16);
}

// -------------------------------------------------------------------------
__global__ __launch_bounds__(256) void cast_f32_bf16(
    const float* __restrict__ in, unsigned short* __restrict__ out, int n) {
    int i = (blockIdx.x * 256 + threadIdx.x) * 4;
    if (i >= n) return;
    float4 v = *(const float4*)(in + i);
    out[i + 0] = f2bf(v.x);
    out[i + 1] = f2bf(v.y);
    out[i + 2] = f2bf(v.z);
    out[i + 3] = f2bf(v.w);
}

// -------------------------------------------------------------------------
__global__ __launch_bounds__(256) void zero_f32(float* __restrict__ p, int n4) {
    int i = blockIdx.x * 256 + threadIdx.x;
    if (i < n4) *(float4*)(p + i * 4) = (float4){0.f, 0.f, 0.f, 0.f};
}

// -------------------------------------------------------------------------
// W_eff[n][k] = bf16( W[n][k] + (1/16) * sum_r BB[n][r] * A[r][k] ), f32 in.
__global__ __launch_bounds__(256) void fold_lora(
    const float* __restrict__ W, const float* __restrict__ Ain,
    const float* __restrict__ Bin, unsigned short* __restrict__ Weff, int NK) {
    int idx = blockIdx.x * 256 + threadIdx.x;
    if (idx >= NK) return;
    int n = idx >> 10;
    int k = idx & 1023;
    float s = 0.f;
#pragma unroll
    for (int r = 0; r < 16; ++r)
        s += Bin[n * 16 + r] * Ain[r * 1024 + k];
    Weff[idx] = f2bf(W[idx] + 0.0625f * s);
}

// -------------------------------------------------------------------------
// C[M][N] = A@B^T + bias. 128x128 tile (gemm1 / qkv). bf16 out.
__global__ __launch_bounds__(256) void gemm_bt_bias(
    const unsigned short* __restrict__ A, const unsigned short* __restrict__ B,
    const float* __restrict__ bias, unsigned short* __restrict__ Cb,
    int M, int N, int K) {
    __shared__ unsigned short sA[128 * 32];
    __shared__ unsigned short sB[128 * 32];
    const int tid = threadIdx.x;
    const int wave = tid >> 6, lane = tid & 63;
    const int quad = lane >> 4, l16 = lane & 15;
    const int m0 = blockIdx.y * 128, n0 = blockIdx.x * 128;
    const int wm = (wave & 1) * 64, wn = (wave >> 1) * 64;

    const int srow = wave * 32 + (lane >> 2);
    const int scol = (lane & 3) * 8;
    const unsigned short* Ag = A + (size_t)(m0 + srow) * K + scol;
    const unsigned short* Bg = B + (size_t)(n0 + srow) * K + scol;
    unsigned short* sAw = sA + wave * 1024;
    unsigned short* sBw = sB + wave * 1024;
    const size_t kjump = (size_t)16 * K;

    f32x4 acc[4][4];
#pragma unroll
    for (int i = 0; i < 4; ++i)
#pragma unroll
        for (int j = 0; j < 4; ++j) acc[i][j] = (f32x4){0.f, 0.f, 0.f, 0.f};

    for (int k0 = 0; k0 < K; k0 += 32) {
        bf16x8 va0 = *(const bf16x8*)(Ag + k0);
        bf16x8 va1 = *(const bf16x8*)(Ag + k0 + kjump);
        bf16x8 vb0 = *(const bf16x8*)(Bg + k0);
        bf16x8 vb1 = *(const bf16x8*)(Bg + k0 + kjump);
        __syncthreads();
        *(bf16x8*)(sAw + (size_t)lane * 8) = va0;
        *(bf16x8*)(sAw + 512 + (size_t)lane * 8) = va1;
        *(bf16x8*)(sBw + (size_t)lane * 8) = vb0;
        *(bf16x8*)(sBw + 512 + (size_t)lane * 8) = vb1;
        __syncthreads();
        bf16x8 af[4], bfr[4];
#pragma unroll
        for (int mi = 0; mi < 4; ++mi)
            af[mi] = *(const bf16x8*)&sA[(wm + mi * 16 + l16) * 32 + quad * 8];
#pragma unroll
        for (int ni = 0; ni < 4; ++ni)
            bfr[ni] = *(const bf16x8*)&sB[(wn + ni * 16 + l16) * 32 + quad * 8];
#pragma unroll
        for (int mi = 0; mi < 4; ++mi)
#pragma unroll
            for (int ni = 0; ni < 4; ++ni)
                acc[mi][ni] = __builtin_amdgcn_mfma_f32_16x16x32_bf16(
                    af[mi], bfr[ni], acc[mi][ni], 0, 0, 0);
    }
    float bv[4];
#pragma unroll
    for (int ni = 0; ni < 4; ++ni) bv[ni] = bias[n0 + wn + ni * 16 + l16];
#pragma unroll
    for (int mi = 0; mi < 4; ++mi)
#pragma unroll
        for (int ni = 0; ni < 4; ++ni)
#pragma unroll
            for (int r = 0; r < 4; ++r) {
                int row = m0 + wm + mi * 16 + quad * 4 + r;
                int col = n0 + wn + ni * 16 + l16;
                Cb[(size_t)row * N + col] = f2bf(acc[mi][ni][r] + bv[ni]);
            }
}

// -------------------------------------------------------------------------
// 64x64-tile GEMM (proj): grid (16,64) = 1024 blocks -> 4 blocks/CU. f32 out.
__global__ __launch_bounds__(256) void gemm_bt_bias64(
    const unsigned short* __restrict__ A, const unsigned short* __restrict__ B,
    const float* __restrict__ bias, float* __restrict__ Cf,
    int M, int N, int K) {
    __shared__ unsigned short sA[64 * 32];
    __shared__ unsigned short sB[64 * 32];
    const int tid = threadIdx.x;
    const int wave = tid >> 6, lane = tid & 63;
    const int quad = lane >> 4, l16 = lane & 15;
    const int m0 = blockIdx.y * 64, n0 = blockIdx.x * 64;
    const int wm = (wave & 1) * 32, wn = (wave >> 1) * 32;

    const int srow = tid >> 2;
    const int scol = (tid & 3) * 8;
    const unsigned short* Ag = A + (size_t)(m0 + srow) * K + scol;
    const unsigned short* Bg = B + (size_t)(n0 + srow) * K + scol;

    f32x4 acc[2][2];
#pragma unroll
    for (int i = 0; i < 2; ++i)
#pragma unroll
        for (int j = 0; j < 2; ++j) acc[i][j] = (f32x4){0.f, 0.f, 0.f, 0.f};

    for (int k0 = 0; k0 < K; k0 += 32) {
        bf16x8 va = *(const bf16x8*)(Ag + k0);
        bf16x8 vb = *(const bf16x8*)(Bg + k0);
        __syncthreads();
        *(bf16x8*)&sA[srow * 32 + scol] = va;
        *(bf16x8*)&sB[srow * 32 + scol] = vb;
        __syncthreads();
        bf16x8 af[2], bfr[2];
#pragma unroll
        for (int mi = 0; mi < 2; ++mi)
            af[mi] = *(const bf16x8*)&sA[(wm + mi * 16 + l16) * 32 + quad * 8];
#pragma unroll
        for (int ni = 0; ni < 2; ++ni)
            bfr[ni] = *(const bf16x8*)&sB[(wn + ni * 16 + l16) * 32 + quad * 8];
#pragma unroll
        for (int mi = 0; mi < 2; ++mi)
#pragma unroll
            for (int ni = 0; ni < 2; ++ni)
                acc[mi][ni] = __builtin_amdgcn_mfma_f32_16x16x32_bf16(
                    af[mi], bfr[ni], acc[mi][ni], 0, 0, 0);
    }
    float bv[2];
#pragma unroll
    for (int ni = 0; ni < 2; ++ni) bv[ni] = bias[n0 + wn + ni * 16 + l16];
#pragma unroll
    for (int mi = 0; mi < 2; ++mi)
#pragma unroll
        for (int ni = 0; ni < 2; ++ni)
#pragma unroll
            for (int r = 0; r < 4; ++r) {
                int row = m0 + wm + mi * 16 + quad * 4 + r;
                int col = n0 + wn + ni * 16 + l16;
                Cf[(size_t)row * N + col] = acc[mi][ni][r] + bv[ni];
            }
}

// -------------------------------------------------------------------------
// Vt[(b*16+h)][d][t] = qkv[b*2048+t][2048 + h*64 + d]   (bf16, verified)
__global__ __launch_bounds__(256) void transpose_v(
    const unsigned short* __restrict__ qkv, unsigned short* __restrict__ Vt) {
    const int b = blockIdx.z, h = blockIdx.y, t0 = blockIdx.x * 64;
    __shared__ unsigned short tile[64][68];
    const int tid = threadIdx.x;
    const int r = tid >> 3, c8 = (tid & 7) * 8;
    const unsigned short* src = qkv + (size_t)(b * 2048) * 3072 + 2048 + h * 64;
#pragma unroll
    for (int p = 0; p < 2; ++p) {
        int t = p * 32 + r;
        const unsigned short* s = src + (size_t)(t0 + t) * 3072 + c8;
#pragma unroll
        for (int j = 0; j < 8; ++j) tile[t][c8 + j] = s[j];
    }
    __syncthreads();
    unsigned short* dst = Vt + (size_t)((b * 16 + h) * 64) * 2048;
#pragma unroll
    for (int p = 0; p < 2; ++p) {
        int d = p * 32 + r;
        unsigned short* o = dst + (size_t)d * 2048 + t0 + c8;
#pragma unroll
        for (int j = 0; j < 8; ++j) o[j] = tile[c8 + j][d];
    }
}

// -------------------------------------------------------------------------
// Split-KV flash attention, register-resident P (no LDS round-trip):
// S^T = mfma(K_frag, Q_frag)  -> (kv = quad*4+r, q = l16), which IS the
// A-operand layout of v_mfma_f32_16x16x16_bf16 (A[m=l16][k=quad*4+j]) with
// m=q, k=kv. So P feeds PV directly from registers:
//   o[nt] = mfma_16x16x16(pf[f], vf[nt][f], o[nt]),  vf = Vt[d][kv] b64 frag.
__global__ __launch_bounds__(256) void attn_chunk(
    const unsigned short* __restrict__ qkv,  // [4096][3072] bf16
    const unsigned short* __restrict__ Vt,   // [32][64][2048] bf16
    float* __restrict__ oacc,                // [4096][1024] f32 (zeroed)
    float* __restrict__ lag) {               // [4096][16] f32 (zeroed)
    const int b = blockIdx.z, h = blockIdx.y;
    const int qblk = blockIdx.x >> 2;
    const int c = blockIdx.x & 3;
    const int t0 = c * 8;
    if (t0 > qblk) return;  // block-uniform early exit
    const int t1 = min(t0 + 8, qblk + 1);

    const int w = threadIdx.x >> 6, lane = threadIdx.x & 63;
    const int quad = lane >> 4, l16 = lane & 15;
    const int q0 = qblk * 64 + w * 16;

    __shared__ unsigned short sK[64 * 72];  // [kv][d]
    __shared__ unsigned short sV[64 * 72];  // [d][kv]

    const unsigned short* Qb = qkv + (size_t)(b * 2048) * 3072 + h * 64;
    const unsigned short* Kg = Qb + 1024;
    const unsigned short* Vg = Vt + (size_t)((b * 16 + h) * 64) * 2048;

    const int rlo = threadIdx.x >> 3;
    const int c8 = (threadIdx.x & 7) * 8;

    bf16x8 qf0 = *(const bf16x8*)(Qb + (size_t)(q0 + l16) * 3072 + quad * 8);
    bf16x8 qf1 = *(const bf16x8*)(Qb + (size_t)(q0 + l16) * 3072 + 32 + quad * 8);

    f32x4 o[4];
    float lsum = 0.f;  // per-lane: q = l16, summed over this lane's kv values
#pragma unroll
    for (int nt = 0; nt < 4; ++nt) o[nt] = (f32x4){0.f, 0.f, 0.f, 0.f};

    const float csc = 0.125f * 1.44269504088896340736f;

    bf16x8 kr0 = *(const bf16x8*)(Kg + (size_t)(t0 * 64 + rlo) * 3072 + c8);
    bf16x8 kr1 = *(const bf16x8*)(Kg + (size_t)(t0 * 64 + rlo + 32) * 3072 + c8);
    bf16x8 vr0 = *(const bf16x8*)(Vg + (size_t)rlo * 2048 + t0 * 64 + c8);
    bf16x8 vr1 = *(const bf16x8*)(Vg + (size_t)(rlo + 32) * 2048 + t0 * 64 + c8);

    for (int it = t0; it < t1; ++it) {
        const int kv0 = it * 64;
        __syncthreads();
        *(bf16x8*)&sK[rlo * 72 + c8] = kr0;
        *(bf16x8*)&sK[(rlo + 32) * 72 + c8] = kr1;
        *(bf16x8*)&sV[rlo * 72 + c8] = vr0;
        *(bf16x8*)&sV[(rlo + 32) * 72 + c8] = vr1;
        if (it + 1 < t1) {
            const int nx = kv0 + 64;
            kr0 = *(const bf16x8*)(Kg + (size_t)(nx + rlo) * 3072 + c8);
            kr1 = *(const bf16x8*)(Kg + (size_t)(nx + rlo + 32) * 3072 + c8);
            vr0 = *(const bf16x8*)(Vg + (size_t)rlo * 2048 + nx + c8);
            vr1 = *(const bf16x8*)(Vg + (size_t)(rlo + 32) * 2048 + nx + c8);
        }
        __syncthreads();

        // S^T tiles: St[f] holds (kv = kv0 + f*16 + quad*4 + r, q = q0 + l16)
        f32x4 St[4];
#pragma unroll
        for (int f = 0; f < 4; ++f) {
            bf16x8 klo = *(const bf16x8*)&sK[(f * 16 + l16) * 72 + quad * 8];
            bf16x8 khi = *(const bf16x8*)&sK[(f * 16 + l16) * 72 + 32 + quad * 8];
            St[f] = (f32x4){0.f, 0.f, 0.f, 0.f};
            St[f] = __builtin_amdgcn_mfma_f32_16x16x32_bf16(klo, qf0, St[f], 0, 0, 0);
            St[f] = __builtin_amdgcn_mfma_f32_16x16x32_bf16(khi, qf1, St[f], 0, 0, 0);
        }
        // mask + exp2 in registers; pack P into 16x16x16 A-operand frags
        bf16x4 pf[4];
        if (it == qblk) {
            const int qr = q0 + l16;
#pragma unroll
            for (int f = 0; f < 4; ++f)
#pragma unroll
                for (int r = 0; r < 4; ++r) {
                    int kv = kv0 + f * 16 + quad * 4 + r;
                    float p = (kv <= qr) ? exp2f(St[f][r] * csc) : 0.f;
                    lsum += p;
                    pf[f][r] = (short)f2bf(p);
                }
        } else {
#pragma unroll
            for (int f = 0; f < 4; ++f)
#pragma unroll
                for (int r = 0; r < 4; ++r) {
                    float p = exp2f(St[f][r] * csc);
                    lsum += p;
                    pf[f][r] = (short)f2bf(p);
                }
        }
        // PV: o[q][d] += P[q][kv] * V[kv][d], P straight from registers
#pragma unroll
        for (int nt = 0; nt < 4; ++nt)
#pragma unroll
            for (int f = 0; f < 4; ++f) {
                bf16x4 vf = *(const bf16x4*)&sV[(nt * 16 + l16) * 72 + f * 16 + quad * 4];
                o[nt] = __builtin_amdgcn_mfma_f32_16x16x16bf16_1k(pf[f], vf, o[nt], 0, 0, 0);
            }
    }

    // denominator: sum the 4 quad-lanes holding the same q = l16
    float lt = lsum;
    lt += __shfl_xor(lt, 16);
    lt += __shfl_xor(lt, 32);
    if (quad == 0)
        atomicAdd(&lag[(b * 2048 + q0 + l16) * 16 + h], lt);

    float* ob = oacc + (size_t)(b * 2048) * 1024 + h * 64;
#pragma unroll
    for (int nt = 0; nt < 4; ++nt)
#pragma unroll
        for (int r = 0; r < 4; ++r)
            atomicAdd(&ob[(size_t)(q0 + quad * 4 + r) * 1024 + nt * 16 + l16],
                      o[nt][r]);
}

// -------------------------------------------------------------------------
// y_bf16[row][ch] = oacc[row][ch] / lag[row*16 + ch/64]
__global__ __launch_bounds__(256) void attn_final(
    const float* __restrict__ oacc, const float* __restrict__ lag,
    unsigned short* __restrict__ y, int n) {
    int i = (blockIdx.x * 256 + threadIdx.x) * 4;
    if (i >= n) return;
    float4 v = *(const float4*)(oacc + i);
    int row = i >> 10, ch = i & 1023;
    float inv = 1.0f / lag[row * 16 + (ch >> 6)];
    y[i + 0] = f2bf(v.x * inv);
    y[i + 1] = f2bf(v.y * inv);
    y[i + 2] = f2bf(v.z * inv);
    y[i + 3] = f2bf(v.w * inv);
}

// -------------------------------------------------------------------------
extern "C" void kernel_launch(void* const* d_in, const int* in_sizes, int n_in,
                              void* d_out, int out_size, void* d_ws, size_t ws_size,
                              hipStream_t stream) {
    const float* x       = (const float*)d_in[0];
    const float* w_attn  = (const float*)d_in[1];
    const float* b_attn  = (const float*)d_in[2];
    const float* la_attn = (const float*)d_in[3];
    const float* lb_attn = (const float*)d_in[4];
    const float* w_proj  = (const float*)d_in[5];
    const float* b_proj  = (const float*)d_in[6];
    const float* la_proj = (const float*)d_in[7];
    const float* lb_proj = (const float*)d_in[8];
    float* out = (float*)d_out;

    // Workspace aliased by lifetime; total ~52.7 MB.
    char* w = (char*)d_ws;
    unsigned short* qkv       = (unsigned short*)(w);             // 24 MB [gemm1..attn_chunk]
    unsigned short* Vt        = (unsigned short*)(w + 25165824);  //  8 MB [transpose..attn_chunk]
    unsigned short* Weff_proj = (unsigned short*)(w + 33554432);  //  2 MB [fold..gemm2]
    char* pool = w + 35651584;                                    // 16.25 MB, two lifetimes:
    unsigned short* xb        = (unsigned short*)(pool);           // 8 MB [cast..gemm1]
    unsigned short* Weff_attn = (unsigned short*)(pool + 8388608); // 6 MB [fold..gemm1]
    float* oacc               = (float*)(pool);                    // 16 MB [zero..attn_final]
    float* lag                = (float*)(pool + 16777216);         // 256 KB (per row,head)
    unsigned short* y = qkv;  // alias; qkv dead after attn_chunk

    cast_f32_bf16<<<4096, 256, 0, stream>>>(x, xb, 4096 * 1024);
    fold_lora<<<(3072 * 1024) / 256, 256, 0, stream>>>(w_attn, la_attn, lb_attn,
                                                       Weff_attn, 3072 * 1024);
    fold_lora<<<(1024 * 1024) / 256, 256, 0, stream>>>(w_proj, la_proj, lb_proj,
                                                       Weff_proj, 1024 * 1024);
    gemm_bt_bias<<<dim3(24, 32), 256, 0, stream>>>(xb, Weff_attn, b_attn, qkv,
                                                   4096, 3072, 1024);
    // pool's first lifetime (xb, Weff_attn) ends; zero it for oacc+lag
    const int accn = 4096 * 1024 + 4096 * 16;  // oacc + lag, contiguous
    zero_f32<<<(accn / 4 + 255) / 256, 256, 0, stream>>>(oacc, accn / 4);
    transpose_v<<<dim3(32, 16, 2), 256, 0, stream>>>(qkv, Vt);
    attn_chunk<<<dim3(128, 16, 2), 256, 0, stream>>>(qkv, Vt, oacc, lag);
    attn_final<<<4096, 256, 0, stream>>>(oacc, lag, y, 4096 * 1024);
    gemm_bt_bias64<<<dim3(16, 64), 256, 0, stream>>>(y, Weff_proj, b_proj, out,
                                                     4096, 1024, 1024);
}